// Round 11
// baseline (99.196 us; speedup 1.0000x reference)
//
#include <hip/hip_runtime.h>

#define TT 128
#define BB 512
#define DD 512
#define HH 512
#define CC 32
#define NQ 10
#define GC 128      // 4 gates * 32 centres
#define DH 1024     // D + H
#define CHUNK 8
#define NCHUNK (TT / CHUNK)
#define HLOC 256    // h-columns per lstm block
#define L2E 1.4426950408889634f
#define KB_PER_B 32768   // bytes of K per batch element (128t x 128gc x f16)

typedef __fp16 h2 __attribute__((ext_vector_type(2)));
typedef __fp16 h4 __attribute__((ext_vector_type(4)));
typedef __fp16 h8 __attribute__((ext_vector_type(8)));
typedef float f4 __attribute__((ext_vector_type(4)));

__device__ __forceinline__ float rcpf(float x) { return __builtin_amdgcn_rcpf(x); }
__device__ __forceinline__ float exp2fast(float x) {
#if __has_builtin(__builtin_amdgcn_exp2f)
    return __builtin_amdgcn_exp2f(x);
#else
    return exp2f(x);
#endif
}

// ---------------- Kernel A: quantum-kernel features, pre-swizzled ----------------
// grid 1024: bid>>1 = b, bid&1 = t-half. Writes K[b] as the exact byte image
// kernel B's Klds wants: byte = b*32768 + ((t*256 + gc*2) ^ ((t&7)<<4)).
__global__ __launch_bounds__(256) void qk_kernel(
    const float* __restrict__ inputs,   // [T][B][D]
    const float* __restrict__ centres,  // [4][C][DH]
    __fp16* __restrict__ kbuf)
{
    __shared__ float xsA[64 * 12];      // 0.5*x rows for this t-half
    __shared__ float csT[NQ * 128];     // 0.5*centres, transposed

    const int bid = blockIdx.x;
    const int b = bid >> 1, th = bid & 1;
    const int tid = threadIdx.x;

    for (int idx = tid; idx < 64 * NQ; idx += 256) {
        int tl = idx / NQ, d = idx - tl * NQ;
        xsA[tl * 12 + d] = 0.5f * inputs[((size_t)(th * 64 + tl) * BB + b) * DD + d];
    }
    for (int idx = tid; idx < GC * NQ; idx += 256) {
        int gc = idx & 127, d = idx >> 7;
        csT[d * 128 + gc] = 0.5f * centres[(size_t)gc * DH + d];
    }
    __syncthreads();

    const int gcq = (tid & 31) * 4;
    const int t0 = tid >> 5;            // 0..7
    char* kb = (char*)kbuf + (size_t)b * KB_PER_B;
    #pragma unroll
    for (int p = 0; p < 8; ++p) {
        const int tl = t0 + p * 8;      // 0..63
        const int t = th * 64 + tl;
        float pr0 = 1.f, pr1 = 1.f, pr2 = 1.f, pr3 = 1.f;
        #pragma unroll
        for (int d = 0; d < NQ; ++d) {
            float xd = xsA[tl * 12 + d];                 // broadcast read
            f4 cd = *(const f4*)&csT[d * 128 + gcq];     // conflict-free b128
            pr0 *= fabsf(__cosf(xd - cd.x));
            pr1 *= fabsf(__cosf(xd - cd.y));
            pr2 *= fabsf(__cosf(xd - cd.z));
            pr3 *= fabsf(__cosf(xd - cd.w));
        }
        h2 lo2 = __builtin_amdgcn_cvt_pkrtz(pr0, pr1);
        h2 hi2 = __builtin_amdgcn_cvt_pkrtz(pr2, pr3);
        h4 kk = { lo2.x, lo2.y, hi2.x, hi2.y };
        int byteo = (t * 256 + gcq * 2) ^ ((t & 7) << 4);
        *(h4*)(kb + byteo) = kk;
    }
}

// ---------------- Kernel B: MFMA pre-activations + LSTM recurrence ----------------
__global__ __launch_bounds__(256, 3) void lstm_kernel(
    const __fp16* __restrict__ kbuf,
    const float* __restrict__ lin_w,    // [4][H][C]
    const float* __restrict__ lin_b,    // [4][H]
    float* __restrict__ out)            // outputs [T][B][H] | h [B][H] | c [B][H]
{
    // 52 KB -> 3 blocks/CU
    __shared__ __fp16 Klds[TT * GC];                         // 32 KB (swizzled image)
    __shared__ __align__(16) unsigned preBx[CHUNK * HLOC * 2]; // 16 KB
    __shared__ float blds[4 * HLOC];                         // 4 KB folded biases

    const int bid = blockIdx.x;
    const int b = bid >> 1;
    const int hbase = (bid & 1) * HLOC;

    const int tid = threadIdx.x;     // 0..255
    const int lane = tid & 63;
    const int w = tid >> 6;          // wave 0..3; owns local h [w*64, w*64+64)
    const int q = lane >> 4;         // 0..3
    const int c16 = lane & 15;
    const int hi = lane >> 5;        // dup-half: 0 computes F,O ; 1 computes si,gg2

    // ---- stage Klds: linear b128 copy of the pre-swizzled K image ----
    {
        const char* src = (const char*)kbuf + (size_t)b * KB_PER_B;
        #pragma unroll
        for (int half = 0; half < 2; ++half) {
            uint4 t0_ = *(const uint4*)(src + (((half * 4 + 0) * 256 + tid) * 16));
            uint4 t1_ = *(const uint4*)(src + (((half * 4 + 1) * 256 + tid) * 16));
            uint4 t2_ = *(const uint4*)(src + (((half * 4 + 2) * 256 + tid) * 16));
            uint4 t3_ = *(const uint4*)(src + (((half * 4 + 3) * 256 + tid) * 16));
            *(uint4*)((char*)Klds + (((half * 4 + 0) * 256 + tid) * 16)) = t0_;
            *(uint4*)((char*)Klds + (((half * 4 + 1) * 256 + tid) * 16)) = t1_;
            *(uint4*)((char*)Klds + (((half * 4 + 2) * 256 + tid) * 16)) = t2_;
            *(uint4*)((char*)Klds + (((half * 4 + 3) * 256 + tid) * 16)) = t3_;
        }
    }

    // ---- folded biases ----
    for (int idx = tid; idx < 4 * HLOC; idx += 256) {
        int g = idx >> 8, hl = idx & 255;
        float s = (g == 2) ? (2.f * L2E) : (-L2E);
        blds[idx] = s * lin_b[g * HH + hbase + hl];
    }

    // ---- B fragments (scale-folded weights): lane = (col c16, k q*8+e) ----
    h8 bfr[16];   // [g*4 + j]
    {
        const int c0 = q * 8;
        #pragma unroll
        for (int g = 0; g < 4; ++g) {
            const float s = (g == 2) ? (2.f * L2E) : (-L2E);
            #pragma unroll
            for (int j = 0; j < 4; ++j) {
                const int hcolg = hbase + w * 64 + j * 16 + c16;
                const float* wp = lin_w + (((size_t)g * HH + hcolg) * CC + c0);
                f4 lo = *(const f4*)wp;
                f4 hif = *(const f4*)(wp + 4);
                h2 p0 = __builtin_amdgcn_cvt_pkrtz(s * lo.x, s * lo.y);
                h2 p1 = __builtin_amdgcn_cvt_pkrtz(s * lo.z, s * lo.w);
                h2 p2 = __builtin_amdgcn_cvt_pkrtz(s * hif.x, s * hif.y);
                h2 p3 = __builtin_amdgcn_cvt_pkrtz(s * hif.z, s * hif.w);
                h8 bb = { p0.x, p0.y, p1.x, p1.y, p2.x, p2.y, p3.x, p3.y };
                bfr[g * 4 + j] = bb;
            }
        }
    }
    __syncthreads();   // Klds staged; last barrier in the kernel

    // ---- per 8-t chunk: MFMA + lane-split activations, then recurrence ----
    float cs2 = 0.f, hstate = 0.f;   // cs2 = 2*log2e*c
    float* op = out + (size_t)b * HH + hbase + tid;
    const int tlo = c16 & 7;         // duplicated A rows (round-7-proven)
    int aoff[4];
    #pragma unroll
    for (int g = 0; g < 4; ++g)
        aoff[g] = tlo * 256 + ((g * 64 + q * 16) ^ (tlo << 4));
    const int hclbase = w * 64 + c16;     // local column
    const int rl0 = (q & 1) * 4;          // t-row base within chunk

    for (int ct = 0; ct < NCHUNK; ++ct) {
        const char* arp = (const char*)Klds + ct * 2048;
        h8 afr[4];
        #pragma unroll
        for (int g = 0; g < 4; ++g)
            afr[g] = *(const h8*)(arp + aoff[g]);

        #pragma unroll
        for (int j = 0; j < 4; ++j) {
            const int hcl = hclbase + j * 16;
            const float bf = blds[0 * HLOC + hcl];
            const float bi = blds[1 * HLOC + hcl];
            const float bg = blds[2 * HLOC + hcl];
            const float bo = blds[3 * HLOC + hcl];
            f4 cf = { bf, bf, bf, bf };
            f4 ci = { bi, bi, bi, bi };
            f4 cg = { bg, bg, bg, bg };
            f4 co = { bo, bo, bo, bo };
            f4 aF = __builtin_amdgcn_mfma_f32_16x16x32_f16(afr[0], bfr[0*4+j], cf, 0, 0, 0);
            f4 aI = __builtin_amdgcn_mfma_f32_16x16x32_f16(afr[1], bfr[1*4+j], ci, 0, 0, 0);
            f4 aG = __builtin_amdgcn_mfma_f32_16x16x32_f16(afr[2], bfr[2*4+j], cg, 0, 0, 0);
            f4 aO = __builtin_amdgcn_mfma_f32_16x16x32_f16(afr[3], bfr[3*4+j], co, 0, 0, 0);
            // Dup lane-pairs (q,q+2) hold identical rows: split the 4 gates.
            // lo (hi=0): e1=F, e2=O ; hi (hi=1): e1=si, e2=rg -> IG2=si*gg2.
            #pragma unroll
            for (int r = 0; r < 4; ++r) {
                float selA = hi ? aI[r] : aF[r];
                float selB = hi ? aG[r] : aO[r];
                float e1 = rcpf(1.f + exp2fast(selA));
                float e2 = rcpf(1.f + exp2fast(selB));
                float gg2 = fmaf(-4.f * L2E, e2, 2.f * L2E);   // 2log2e*tanh(g)
                float ig2 = e1 * gg2;                          // si*gg2 (hi only)
                h2 pk = __builtin_amdgcn_cvt_pkrtz(e1, e2);    // (F,O)  (lo only)
                unsigned uval = hi ? __builtin_bit_cast(unsigned, ig2)
                                   : *(unsigned*)&pk;
                preBx[((rl0 + r) * HLOC + hcl) * 2 + hi] = uval;  // unmasked b32
            }
        }

        // recurrence: thread = local h, 8 steps, 1 ds_read_b64 each.
        // preBx columns wave-private; same-wave LDS in-order -> no barrier.
        #pragma unroll
        for (int s = 0; s < CHUNK; ++s) {
            uint2 vv = *(const uint2*)&preBx[(s * HLOC + tid) * 2];
            h2 fo = *(h2*)&vv.x;
            float F = (float)fo.x;
            float O = (float)fo.y;
            float IG2 = __builtin_bit_cast(float, vv.y);
            cs2 = fmaf(F, cs2, IG2);
            float th = fmaf(-2.f, rcpf(1.f + exp2fast(cs2)), 1.f);
            hstate = O * th;
            op[(size_t)(ct * CHUNK + s) * (BB * HH)] = hstate;
        }
    }

    float* hout = out + (size_t)TT * BB * HH;
    float* cout = hout + (size_t)BB * HH;
    hout[(size_t)b * HH + hbase + tid] = hstate;
    cout[(size_t)b * HH + hbase + tid] = cs2 * 0.34657359027997264f; // /(2*log2e)
}

extern "C" void kernel_launch(void* const* d_in, const int* in_sizes, int n_in,
                              void* d_out, int out_size, void* d_ws, size_t ws_size,
                              hipStream_t stream) {
    const float* inputs  = (const float*)d_in[0];
    const float* centres = (const float*)d_in[1];
    const float* lin_w   = (const float*)d_in[2];
    const float* lin_b   = (const float*)d_in[3];
    float* out = (float*)d_out;

    // K scratch: 512 * 32 KB = 16.8 MB. Prefer d_ws; fall back to the tail of
    // the outputs region (out[112..128][*][*]), which kernel B only writes in
    // its final two chunks, after every block has staged its K image.
    const size_t KBYTES = (size_t)BB * KB_PER_B;
    void* kbuf = (ws_size >= KBYTES)
               ? d_ws
               : (void*)((char*)d_out + (size_t)112 * BB * HH * sizeof(float));

    qk_kernel<<<dim3(1024), dim3(256), 0, stream>>>(inputs, centres, (__fp16*)kbuf);
    lstm_kernel<<<dim3(1024), dim3(256), 0, stream>>>((const __fp16*)kbuf, lin_w, lin_b, out);
}

// Round 12
// 93.916 us; speedup vs baseline: 1.0562x; 1.0562x over previous
//
#include <hip/hip_runtime.h>

#define TT 128
#define BB 512
#define DD 512
#define HH 512
#define CC 32
#define NQ 10
#define GC 128      // 4 gates * 32 centres
#define DH 1024     // D + H
#define CHUNK 8
#define NCHUNK (TT / CHUNK)
#define HLOC 256    // h-columns per lstm block
#define L2E 1.4426950408889634f
#define K_ELEMS_PER_B (TT * GC)          // 16384 f16 per batch element

typedef __fp16 h2 __attribute__((ext_vector_type(2)));
typedef __fp16 h4 __attribute__((ext_vector_type(4)));
typedef __fp16 h8 __attribute__((ext_vector_type(8)));
typedef float f4 __attribute__((ext_vector_type(4)));

__device__ __forceinline__ float rcpf(float x) { return __builtin_amdgcn_rcpf(x); }
__device__ __forceinline__ float exp2fast(float x) {
#if __has_builtin(__builtin_amdgcn_exp2f)
    return __builtin_amdgcn_exp2f(x);
#else
    return exp2f(x);
#endif
}

// ---------------- Kernel A: quantum-kernel features, LINEAR layout ----------------
// grid 1024: bid>>1 = b, bid&1 = t-half. kbuf[b][t][gc] f16, row-major.
__global__ __launch_bounds__(256) void qk_kernel(
    const float* __restrict__ inputs,   // [T][B][D]
    const float* __restrict__ centres,  // [4][C][DH]
    __fp16* __restrict__ kbuf)
{
    __shared__ float xsA[64 * 12];      // 0.5*x rows for this t-half
    __shared__ float csT[NQ * 128];     // 0.5*centres, transposed

    const int bid = blockIdx.x;
    const int b = bid >> 1, th = bid & 1;
    const int tid = threadIdx.x;

    for (int idx = tid; idx < 64 * NQ; idx += 256) {
        int tl = idx / NQ, d = idx - tl * NQ;
        xsA[tl * 12 + d] = 0.5f * inputs[((size_t)(th * 64 + tl) * BB + b) * DD + d];
    }
    for (int idx = tid; idx < GC * NQ; idx += 256) {
        int gc = idx & 127, d = idx >> 7;
        csT[d * 128 + gc] = 0.5f * centres[(size_t)gc * DH + d];
    }
    __syncthreads();

    const int gcq = (tid & 31) * 4;
    const int t0 = tid >> 5;            // 0..7
    __fp16* kb = kbuf + (size_t)b * K_ELEMS_PER_B;
    #pragma unroll
    for (int p = 0; p < 8; ++p) {
        const int tl = t0 + p * 8;      // 0..63
        const int t = th * 64 + tl;
        float pr0 = 1.f, pr1 = 1.f, pr2 = 1.f, pr3 = 1.f;
        #pragma unroll
        for (int d = 0; d < NQ; ++d) {
            float xd = xsA[tl * 12 + d];                 // broadcast read
            f4 cd = *(const f4*)&csT[d * 128 + gcq];     // conflict-free b128
            pr0 *= fabsf(__cosf(xd - cd.x));
            pr1 *= fabsf(__cosf(xd - cd.y));
            pr2 *= fabsf(__cosf(xd - cd.z));
            pr3 *= fabsf(__cosf(xd - cd.w));
        }
        h2 lo2 = __builtin_amdgcn_cvt_pkrtz(pr0, pr1);
        h2 hi2 = __builtin_amdgcn_cvt_pkrtz(pr2, pr3);
        h4 kk = { lo2.x, lo2.y, hi2.x, hi2.y };
        *(h4*)(kb + t * GC + gcq) = kk;                  // coalesced 8B store
    }
}

// ---------------- Kernel B: MFMA pre-activations + LSTM recurrence ----------------
// grid 1024: b = bid&511 (bid and bid+512 -> SAME XCD -> shared L2 K image),
// hbase = (bid>>9)*256. LDS 16 KB, target 4 blocks/CU (128-reg band).
__global__ __launch_bounds__(256, 4) void lstm_kernel(
    const __fp16* __restrict__ kbuf,
    const float* __restrict__ lin_w,    // [4][H][C]
    const float* __restrict__ lin_b,    // [4][H]
    float* __restrict__ out)            // outputs [T][B][H] | h [B][H] | c [B][H]
{
    __shared__ __align__(16) unsigned preBx[CHUNK * HLOC * 2]; // 16 KB

    const int bid = blockIdx.x;
    const int b = bid & 511;
    const int hbase = (bid >> 9) * HLOC;

    const int tid = threadIdx.x;     // 0..255
    const int lane = tid & 63;
    const int w = tid >> 6;          // wave 0..3; owns local h [w*64, w*64+64)
    const int q = lane >> 4;         // 0..3
    const int c16 = lane & 15;
    const int hi = lane >> 5;        // dup-half: 0 computes F,O ; 1 computes si,gg2

    // ---- B fragments (scale-folded f16 weights; expect AGPR residency) ----
    h8 bfr[16];      // [g*4 + j]
    float bA[4], bB[4];   // lane-selected post-MFMA biases per j
    {
        const int c0 = q * 8;
        #pragma unroll
        for (int g = 0; g < 4; ++g) {
            const float s = (g == 2) ? (2.f * L2E) : (-L2E);
            #pragma unroll
            for (int j = 0; j < 4; ++j) {
                const int hcolg = hbase + w * 64 + j * 16 + c16;
                const float* wp = lin_w + (((size_t)g * HH + hcolg) * CC + c0);
                f4 lo = *(const f4*)wp;
                f4 hif = *(const f4*)(wp + 4);
                h2 p0 = __builtin_amdgcn_cvt_pkrtz(s * lo.x, s * lo.y);
                h2 p1 = __builtin_amdgcn_cvt_pkrtz(s * lo.z, s * lo.w);
                h2 p2 = __builtin_amdgcn_cvt_pkrtz(s * hif.x, s * hif.y);
                h2 p3 = __builtin_amdgcn_cvt_pkrtz(s * hif.z, s * hif.w);
                h8 bb = { p0.x, p0.y, p1.x, p1.y, p2.x, p2.y, p3.x, p3.y };
                bfr[g * 4 + j] = bb;
            }
        }
        #pragma unroll
        for (int j = 0; j < 4; ++j) {
            const int hcolg = hbase + w * 64 + j * 16 + c16;
            float bf_ = -L2E * lin_b[0 * HH + hcolg];
            float bi_ = -L2E * lin_b[1 * HH + hcolg];
            float bg_ = 2.f * L2E * lin_b[2 * HH + hcolg];
            float bo_ = -L2E * lin_b[3 * HH + hcolg];
            bA[j] = hi ? bi_ : bf_;
            bB[j] = hi ? bg_ : bo_;
        }
    }

    float cs2 = 0.f, hstate = 0.f;   // cs2 = 2*log2e*c
    float* op = out + (size_t)b * HH + hbase + tid;
    const int tlo = c16 & 7;         // duplicated A rows (round-7-proven layout)
    const __fp16* kb = kbuf + (size_t)b * K_ELEMS_PER_B + tlo * GC + q * 8;
    const int hclbase = w * 64 + c16;     // local column
    const int rl0 = (q & 1) * 4;          // t-row base within chunk

    // ---------- software pipeline over 16 chunks ----------
    h8 afr[4];
    #pragma unroll
    for (int g = 0; g < 4; ++g)
        afr[g] = *(const h8*)(kb + g * 32);        // chunk 0 A-fragments

    for (int ct = 0; ct < NCHUNK; ++ct) {
        // ---- MFMA + lane-split activations -> preBx (this chunk) ----
        #pragma unroll
        for (int j = 0; j < 4; ++j) {
            const int hcl = hclbase + j * 16;
            const f4 z4 = {0.f, 0.f, 0.f, 0.f};
            f4 aF = __builtin_amdgcn_mfma_f32_16x16x32_f16(afr[0], bfr[0*4+j], z4, 0, 0, 0);
            f4 aI = __builtin_amdgcn_mfma_f32_16x16x32_f16(afr[1], bfr[1*4+j], z4, 0, 0, 0);
            f4 aG = __builtin_amdgcn_mfma_f32_16x16x32_f16(afr[2], bfr[2*4+j], z4, 0, 0, 0);
            f4 aO = __builtin_amdgcn_mfma_f32_16x16x32_f16(afr[3], bfr[3*4+j], z4, 0, 0, 0);
            // Dup lane-pairs (q, q+2) hold identical rows: split the 4 gates.
            #pragma unroll
            for (int r = 0; r < 4; ++r) {
                float selA = (hi ? aI[r] : aF[r]) + bA[j];
                float selB = (hi ? aG[r] : aO[r]) + bB[j];
                float e1 = rcpf(1.f + exp2fast(selA));
                float e2 = rcpf(1.f + exp2fast(selB));
                float gg2 = fmaf(-4.f * L2E, e2, 2.f * L2E);   // 2log2e*tanh(g)
                float ig2 = e1 * gg2;                          // si*gg2 (hi lanes)
                h2 pk = __builtin_amdgcn_cvt_pkrtz(e1, e2);    // (F,O)  (lo lanes)
                unsigned uval = hi ? __builtin_bit_cast(unsigned, ig2)
                                   : *(unsigned*)&pk;
                preBx[((rl0 + r) * HLOC + hcl) * 2 + hi] = uval;
            }
        }

        // ---- prefetch next chunk's A-fragments (latency hidden by recurrence) ----
        if (ct + 1 < NCHUNK) {
            const __fp16* kn = kb + (ct + 1) * (CHUNK * GC);
            #pragma unroll
            for (int g = 0; g < 4; ++g)
                afr[g] = *(const h8*)(kn + g * 32);
        }

        // ---- recurrence for THIS chunk (same-wave LDS ordering, no barrier) ----
        #pragma unroll
        for (int s = 0; s < CHUNK; ++s) {
            uint2 vv = *(const uint2*)&preBx[(s * HLOC + tid) * 2];
            h2 fo = *(h2*)&vv.x;
            float F = (float)fo.x;
            float O = (float)fo.y;
            float IG2 = __builtin_bit_cast(float, vv.y);
            cs2 = fmaf(F, cs2, IG2);
            float th = fmaf(-2.f, rcpf(1.f + exp2fast(cs2)), 1.f);
            hstate = O * th;
            op[(size_t)(ct * CHUNK + s) * (BB * HH)] = hstate;
        }
    }

    float* hout = out + (size_t)TT * BB * HH;
    float* cout = hout + (size_t)BB * HH;
    hout[(size_t)b * HH + hbase + tid] = hstate;
    cout[(size_t)b * HH + hbase + tid] = cs2 * 0.34657359027997264f; // /(2*log2e)
}

extern "C" void kernel_launch(void* const* d_in, const int* in_sizes, int n_in,
                              void* d_out, int out_size, void* d_ws, size_t ws_size,
                              hipStream_t stream) {
    const float* inputs  = (const float*)d_in[0];
    const float* centres = (const float*)d_in[1];
    const float* lin_w   = (const float*)d_in[2];
    const float* lin_b   = (const float*)d_in[3];
    float* out = (float*)d_out;

    // K scratch: 512 * 32 KB = 16.8 MB. Prefer d_ws; fall back to the tail of
    // the outputs region (out[112..128][*][*]), which kernel B only writes in
    // its final two chunks, after staging... (B reads K per-chunk now, so the
    // fallback region must not be clobbered before it is read: B reads chunk
    // 14-15 K late, writes out[112..) late too — same-block ordering is safe,
    // cross-block b!=b' regions don't overlap. Prefer d_ws whenever possible.)
    const size_t KBYTES = (size_t)BB * K_ELEMS_PER_B * sizeof(__fp16);
    void* kbuf = (ws_size >= KBYTES)
               ? d_ws
               : (void*)((char*)d_out + (size_t)112 * BB * HH * sizeof(float));

    qk_kernel<<<dim3(1024), dim3(256), 0, stream>>>(inputs, centres, (__fp16*)kbuf);
    lstm_kernel<<<dim3(1024), dim3(256), 0, stream>>>((const __fp16*)kbuf, lin_w, lin_b, out);
}

// Round 13
// 92.217 us; speedup vs baseline: 1.0757x; 1.0184x over previous
//
#include <hip/hip_runtime.h>

#define TT 128
#define BB 512
#define DD 512
#define HH 512
#define CC 32
#define NQ 10
#define GC 128      // 4 gates * 32 centres
#define DH 1024     // D + H
#define CHUNK 8
#define NCHUNK (TT / CHUNK)
#define HLOC 256    // h-columns per lstm block
#define L2E 1.4426950408889634f
#define K_ELEMS_PER_B (TT * GC)          // 16384 f16 per batch element

typedef __fp16 h2 __attribute__((ext_vector_type(2)));
typedef __fp16 h4 __attribute__((ext_vector_type(4)));
typedef __fp16 h8 __attribute__((ext_vector_type(8)));
typedef float f4 __attribute__((ext_vector_type(4)));

__device__ __forceinline__ float rcpf(float x) { return __builtin_amdgcn_rcpf(x); }
__device__ __forceinline__ float exp2fast(float x) {
#if __has_builtin(__builtin_amdgcn_exp2f)
    return __builtin_amdgcn_exp2f(x);
#else
    return exp2f(x);
#endif
}

// ---------------- Kernel A: quantum-kernel features, LINEAR layout ----------------
// grid 1024: bid>>1 = b, bid&1 = t-half. kbuf[b][t][gc] f16, row-major.
__global__ __launch_bounds__(256) void qk_kernel(
    const float* __restrict__ inputs,   // [T][B][D]
    const float* __restrict__ centres,  // [4][C][DH]
    __fp16* __restrict__ kbuf)
{
    __shared__ float xsA[64 * 12];      // 0.5*x rows for this t-half
    __shared__ float csT[NQ * 128];     // 0.5*centres, transposed

    const int bid = blockIdx.x;
    const int b = bid >> 1, th = bid & 1;
    const int tid = threadIdx.x;

    for (int idx = tid; idx < 64 * NQ; idx += 256) {
        int tl = idx / NQ, d = idx - tl * NQ;
        xsA[tl * 12 + d] = 0.5f * inputs[((size_t)(th * 64 + tl) * BB + b) * DD + d];
    }
    for (int idx = tid; idx < GC * NQ; idx += 256) {
        int gc = idx & 127, d = idx >> 7;
        csT[d * 128 + gc] = 0.5f * centres[(size_t)gc * DH + d];
    }
    __syncthreads();

    const int gcq = (tid & 31) * 4;
    const int t0 = tid >> 5;            // 0..7
    __fp16* kb = kbuf + (size_t)b * K_ELEMS_PER_B;
    #pragma unroll
    for (int p = 0; p < 8; ++p) {
        const int tl = t0 + p * 8;      // 0..63
        const int t = th * 64 + tl;
        float pr0 = 1.f, pr1 = 1.f, pr2 = 1.f, pr3 = 1.f;
        #pragma unroll
        for (int d = 0; d < NQ; ++d) {
            float xd = xsA[tl * 12 + d];                 // broadcast read
            f4 cd = *(const f4*)&csT[d * 128 + gcq];     // conflict-free b128
            pr0 *= fabsf(__cosf(xd - cd.x));
            pr1 *= fabsf(__cosf(xd - cd.y));
            pr2 *= fabsf(__cosf(xd - cd.z));
            pr3 *= fabsf(__cosf(xd - cd.w));
        }
        h2 lo2 = __builtin_amdgcn_cvt_pkrtz(pr0, pr1);
        h2 hi2 = __builtin_amdgcn_cvt_pkrtz(pr2, pr3);
        h4 kk = { lo2.x, lo2.y, hi2.x, hi2.y };
        *(h4*)(kb + t * GC + gcq) = kk;                  // coalesced 8B store
    }
}

// ---------------- Kernel B: MFMA pre-activations + LSTM recurrence ----------------
// grid 1024: b = bid&511, hbase = (bid>>9)*256. LDS 24 KB, 128-reg band.
__global__ __launch_bounds__(256, 4) void lstm_kernel(
    const __fp16* __restrict__ kbuf,
    const float* __restrict__ lin_w,    // [4][H][C]
    const float* __restrict__ lin_b,    // [4][H]
    float* __restrict__ out)            // outputs [T][B][H] | h [B][H] | c [B][H]
{
    // Three stride-1 f32 mailboxes: conflict-free b32 reads AND writes.
    __shared__ float Flds[CHUNK * HLOC];   // 8 KB  sigma(f)
    __shared__ float Ilds[CHUNK * HLOC];   // 8 KB  2log2e*sigma(i)*tanh(g)
    __shared__ float Olds[CHUNK * HLOC];   // 8 KB  sigma(o)

    const int bid = blockIdx.x;
    const int b = bid & 511;
    const int hbase = (bid >> 9) * HLOC;

    const int tid = threadIdx.x;     // 0..255
    const int lane = tid & 63;
    const int w = tid >> 6;          // wave 0..3; owns local h [w*64, w*64+64)
    const int q = lane >> 4;         // 0..3
    const int c16 = lane & 15;
    const int hi = lane >> 5;        // dup-half: 0 -> F,O ; 1 -> IG2

    // ---- B fragments (scale-folded f16 weights; AGPR residency) ----
    h8 bfr[16];      // [g*4 + j]
    float bA[4], bB[4];   // lane-selected post-MFMA biases per j
    {
        const int c0 = q * 8;
        #pragma unroll
        for (int g = 0; g < 4; ++g) {
            const float s = (g == 2) ? (2.f * L2E) : (-L2E);
            #pragma unroll
            for (int j = 0; j < 4; ++j) {
                const int hcolg = hbase + w * 64 + j * 16 + c16;
                const float* wp = lin_w + (((size_t)g * HH + hcolg) * CC + c0);
                f4 lo = *(const f4*)wp;
                f4 hif = *(const f4*)(wp + 4);
                h2 p0 = __builtin_amdgcn_cvt_pkrtz(s * lo.x, s * lo.y);
                h2 p1 = __builtin_amdgcn_cvt_pkrtz(s * lo.z, s * lo.w);
                h2 p2 = __builtin_amdgcn_cvt_pkrtz(s * hif.x, s * hif.y);
                h2 p3 = __builtin_amdgcn_cvt_pkrtz(s * hif.z, s * hif.w);
                h8 bb = { p0.x, p0.y, p1.x, p1.y, p2.x, p2.y, p3.x, p3.y };
                bfr[g * 4 + j] = bb;
            }
        }
        #pragma unroll
        for (int j = 0; j < 4; ++j) {
            const int hcolg = hbase + w * 64 + j * 16 + c16;
            float bf_ = -L2E * lin_b[0 * HH + hcolg];
            float bi_ = -L2E * lin_b[1 * HH + hcolg];
            float bg_ = 2.f * L2E * lin_b[2 * HH + hcolg];
            float bo_ = -L2E * lin_b[3 * HH + hcolg];
            bA[j] = hi ? bi_ : bf_;
            bB[j] = hi ? bg_ : bo_;
        }
    }

    float cs2 = 0.f, hstate = 0.f;   // cs2 = 2*log2e*c
    float* op = out + (size_t)b * HH + hbase + tid;
    const int tlo = c16 & 7;         // duplicated A rows (round-7-proven layout)
    const __fp16* kb = kbuf + (size_t)b * K_ELEMS_PER_B + tlo * GC + q * 8;
    const int hclbase = w * 64 + c16;     // local column
    const int rl0 = (q & 1) * 4;          // t-row base within chunk

    // ---------- software pipeline over 16 chunks ----------
    h8 afr[4];
    #pragma unroll
    for (int g = 0; g < 4; ++g)
        afr[g] = *(const h8*)(kb + g * 32);        // chunk 0 A-fragments

    for (int ct = 0; ct < NCHUNK; ++ct) {
        // ---- MFMA + lane-split activations -> f32 mailboxes ----
        #pragma unroll
        for (int j = 0; j < 4; ++j) {
            const int hcl = hclbase + j * 16;
            const f4 z4 = {0.f, 0.f, 0.f, 0.f};
            f4 aF = __builtin_amdgcn_mfma_f32_16x16x32_f16(afr[0], bfr[0*4+j], z4, 0, 0, 0);
            f4 aI = __builtin_amdgcn_mfma_f32_16x16x32_f16(afr[1], bfr[1*4+j], z4, 0, 0, 0);
            f4 aG = __builtin_amdgcn_mfma_f32_16x16x32_f16(afr[2], bfr[2*4+j], z4, 0, 0, 0);
            f4 aO = __builtin_amdgcn_mfma_f32_16x16x32_f16(afr[3], bfr[3*4+j], z4, 0, 0, 0);
            // Dup lane-pairs (q, q+2) hold identical rows: split the 4 gates.
            #pragma unroll
            for (int r = 0; r < 4; ++r) {
                float selA = (hi ? aI[r] : aF[r]) + bA[j];
                float selB = (hi ? aG[r] : aO[r]) + bB[j];
                float e1 = rcpf(1.f + exp2fast(selA));
                float e2 = rcpf(1.f + exp2fast(selB));
                const int slot = (rl0 + r) * HLOC + hcl;
                if (hi) {
                    float gg2 = fmaf(-4.f * L2E, e2, 2.f * L2E);  // 2log2e*tanh(g)
                    Ilds[slot] = e1 * gg2;                        // si*gg2
                } else {
                    Flds[slot] = e1;                              // sigma(f)
                    Olds[slot] = e2;                              // sigma(o)
                }
            }
        }

        // ---- prefetch next chunk's A-fragments ----
        if (ct + 1 < NCHUNK) {
            const __fp16* kn = kb + (ct + 1) * (CHUNK * GC);
            #pragma unroll
            for (int g = 0; g < 4; ++g)
                afr[g] = *(const h8*)(kn + g * 32);
        }

        // ---- recurrence: 3 conflict-free b32 reads per step, no barrier ----
        #pragma unroll
        for (int s = 0; s < CHUNK; ++s) {
            float F   = Flds[s * HLOC + tid];
            float IG2 = Ilds[s * HLOC + tid];
            float O   = Olds[s * HLOC + tid];
            cs2 = fmaf(F, cs2, IG2);
            float th = fmaf(-2.f, rcpf(1.f + exp2fast(cs2)), 1.f);
            hstate = O * th;
            op[(size_t)(ct * CHUNK + s) * (BB * HH)] = hstate;
        }
    }

    float* hout = out + (size_t)TT * BB * HH;
    float* cout = hout + (size_t)BB * HH;
    hout[(size_t)b * HH + hbase + tid] = hstate;
    cout[(size_t)b * HH + hbase + tid] = cs2 * 0.34657359027997264f; // /(2*log2e)
}

extern "C" void kernel_launch(void* const* d_in, const int* in_sizes, int n_in,
                              void* d_out, int out_size, void* d_ws, size_t ws_size,
                              hipStream_t stream) {
    const float* inputs  = (const float*)d_in[0];
    const float* centres = (const float*)d_in[1];
    const float* lin_w   = (const float*)d_in[2];
    const float* lin_b   = (const float*)d_in[3];
    float* out = (float*)d_out;

    // K scratch: 512 * 32 KB = 16.8 MB. Prefer d_ws; fall back to the tail of
    // the outputs region (out[112..128][*][*]): each lstm block reads its K
    // chunks strictly before writing out rows 112+ for the same b, and
    // cross-b regions don't overlap.
    const size_t KBYTES = (size_t)BB * K_ELEMS_PER_B * sizeof(__fp16);
    void* kbuf = (ws_size >= KBYTES)
               ? d_ws
               : (void*)((char*)d_out + (size_t)112 * BB * HH * sizeof(float));

    qk_kernel<<<dim3(1024), dim3(256), 0, stream>>>(inputs, centres, (__fp16*)kbuf);
    lstm_kernel<<<dim3(1024), dim3(256), 0, stream>>>((const __fp16*)kbuf, lin_w, lin_b, out);
}